// Round 3
// baseline (817.610 us; speedup 1.0000x reference)
//
#include <hip/hip_runtime.h>
#include <cstdint>
#include <cstddef>

typedef unsigned short u16;
typedef unsigned int   u32;

#define LW     15
#define BNS    0.9999950000374997f   /* 1/sqrt(1+1e-5) */
#define SCALE  0.17677669529663687f  /* 1/sqrt(32) */

typedef __bf16 bf16x8 __attribute__((ext_vector_type(8)));
typedef float  f32x4  __attribute__((ext_vector_type(4)));

__device__ __forceinline__ u16 f2bf(float f){
  union { float f; u32 i; } v; v.f = f;
  u32 r = v.i + 0x7FFFu + ((v.i >> 16) & 1u);
  return (u16)(r >> 16);
}
__device__ __forceinline__ float bf2f(u16 u){
  union { u32 i; float f; } v; v.i = ((u32)u) << 16; return v.f;
}

// ---------------------------------------------------------------------------
// Kernel 0: convert qkv_w (196608) and proj_w (65536) fp32 -> bf16 in ws
// ---------------------------------------------------------------------------
__global__ void k_cvt_w(const float* __restrict__ qw, const float* __restrict__ pw,
                        u16* __restrict__ qwb, u16* __restrict__ pwb){
  const int i = blockIdx.x*256 + threadIdx.x;
  if (i < 196608) qwb[i] = f2bf(qw[i]);
  else            pwb[i - 196608] = f2bf(pw[i - 196608]);
}

// ---------------------------------------------------------------------------
// Kernel 1: CPB MLP -> tab[225][8] fp32
// ---------------------------------------------------------------------------
__global__ void k_cpb_mlp(const float* __restrict__ w1, const float* __restrict__ b1,
                          const float* __restrict__ w2, float* __restrict__ tab){
  const int e = blockIdx.x;        // 0..224, e = ti*15 + tj
  const int c = threadIdx.x;       // 0..255
  const float a0 = (float)(e / LW - 7);
  const float a1 = (float)(e % LW - 7);
  const float cx = copysignf(log2f(fabsf(a0)*(8.f/7.f) + 1.f) * (1.f/3.f), a0);
  const float cy = copysignf(log2f(fabsf(a1)*(8.f/7.f) + 1.f) * (1.f/3.f), a1);
  float pre = (cx*w1[2*c] + cy*w1[2*c+1] + b1[c]) * BNS;
  float hid = pre / (1.f + __expf(-pre));   // silu
  __shared__ float hl[256];
  hl[c] = hid;
  __syncthreads();
  if (c < 8){
    float s = 0.f;
    for (int i = 0; i < 256; ++i) s += hl[i] * w2[c*256 + i];
    tab[e*8 + c] = s * BNS;
  }
}

// ---------------------------------------------------------------------------
// Kernel 2: expand to biasT[h][key m][query n] = 16*sigmoid(tab[rpi(n,m)][h])
// ---------------------------------------------------------------------------
__global__ void k_bias_expand(const float* __restrict__ tab, float* __restrict__ biasT){
  const int id = blockIdx.x*256 + threadIdx.x;   // h*4096 + m*64 + n
  const int nq = id & 63;          // query token
  const int m  = (id >> 6) & 63;   // key token
  const int h  = id >> 12;
  const int dy = (nq >> 3) - (m >> 3) + 7;
  const int dx = (nq & 7)  - (m & 7)  + 7;
  const float v = tab[(dy*LW + dx)*8 + h];
  biasT[id] = 16.f / (1.f + __expf(-v));
}

// ---------------------------------------------------------------------------
// Kernel 3: fused qkv GEMM (MFMA) + windowed attention.
// One block per window (256 thr = 4 waves). Per head: 96x64x256 GEMM into
// fp32 LDS (q,k,v), then attention with 4 threads per query token.
// xout = d_out fp32 (attn output, NCHW), vout = vimg bf16 in ws.
// Static LDS: 33792 + 3*9216 = 61440 B.
// ---------------------------------------------------------------------------
__global__ __launch_bounds__(256) void k_qkv_attn(
    const float* __restrict__ x, const u16* __restrict__ qwb,
    const float* __restrict__ qb, const float* __restrict__ biasT,
    float* __restrict__ xout, u16* __restrict__ vout){
  const int win = blockIdx.x;
  const int b = win >> 6, wy = (win >> 3) & 7, wx = win & 7;
  __shared__ __align__(16) u16   xs[64*264];   // [token n][c] bf16, +8 pad
  __shared__ __align__(16) float qs[64*36];    // [token n][d] fp32, +4 pad
  __shared__ __align__(16) float ks[64*36];
  __shared__ __align__(16) float vs[64*36];

  const float* xbase = x + (size_t)b*256*4096 + (size_t)(wy*8)*64 + wx*8;
  for (int i = threadIdx.x; i < 16384; i += 256){
    const int c = i >> 6, n = i & 63;
    xs[n*264 + c] = f2bf(xbase[(size_t)c*4096 + ((n>>3)<<6) + (n&7)]);
  }
  const int wave = threadIdx.x >> 6, lane = threadIdx.x & 63;
  const int quad = lane >> 4, l16 = lane & 15;
  const int tn = threadIdx.x >> 2;   // query token (4 threads each)
  const int kq = threadIdx.x & 3;    // key quarter
  const int pix = ((wy*8 + (tn >> 3))<<6) + wx*8 + (tn & 7);
  __syncthreads();

  for (int h = 0; h < 8; ++h){
    // ---- GEMM: rows 0..31 = q dims, 32..63 = k, 64..95 = v; cols = tokens
    for (int idx = 0; idx < 6; ++idx){
      const int job = wave*6 + idx;      // 24 jobs: ot(0..5) x nt(0..3)
      const int ot = job >> 2, nt = job & 3;
      const int ra = ot*16 + l16;
      const int oga = (ra >> 5)*256 + h*32 + (ra & 31);
      f32x4 acc = {0.f, 0.f, 0.f, 0.f};
      #pragma unroll
      for (int kc = 0; kc < 8; ++kc){
        bf16x8 af = *(const bf16x8*)(qwb + (size_t)oga*256 + kc*32 + quad*8);
        bf16x8 bf = *(const bf16x8*)(&xs[(nt*16 + l16)*264 + kc*32 + quad*8]);
        acc = __builtin_amdgcn_mfma_f32_16x16x32_bf16(af, bf, acc, 0, 0, 0);
      }
      float* dst = (ot < 2) ? qs : (ot < 4) ? ks : vs;
      #pragma unroll
      for (int rr = 0; rr < 4; ++rr){
        const int r = ot*16 + quad*4 + rr;
        const int og = (r >> 5)*256 + h*32 + (r & 31);
        dst[(nt*16 + l16)*36 + (r & 31)] = acc[rr] + qb[og];
      }
    }
    __syncthreads();

    // ---- attention: thread = (query tn, key-quarter kq) ----
    float q[32];
    #pragma unroll
    for (int dd = 0; dd < 8; ++dd){
      const float4 t4 = *(const float4*)&qs[tn*36 + dd*4];
      q[dd*4+0] = t4.x; q[dd*4+1] = t4.y; q[dd*4+2] = t4.z; q[dd*4+3] = t4.w;
    }
    const float* bp = biasT + (h << 12) + tn;
    float s[16], lmax = -1e30f;
    #pragma unroll
    for (int j0 = 0; j0 < 16; ++j0){
      const int j = kq*16 + j0;
      float a = 0.f;
      #pragma unroll
      for (int dd = 0; dd < 8; ++dd){
        const float4 kk = *(const float4*)&ks[j*36 + dd*4];
        a += q[dd*4+0]*kk.x + q[dd*4+1]*kk.y + q[dd*4+2]*kk.z + q[dd*4+3]*kk.w;
      }
      const float sc = a*SCALE + bp[j << 6];
      s[j0] = sc; lmax = fmaxf(lmax, sc);
    }
    lmax = fmaxf(lmax, __shfl_xor(lmax, 1, 64));
    lmax = fmaxf(lmax, __shfl_xor(lmax, 2, 64));
    float lsum = 0.f;
    #pragma unroll
    for (int j0 = 0; j0 < 16; ++j0){ s[j0] = __expf(s[j0] - lmax); lsum += s[j0]; }
    lsum += __shfl_xor(lsum, 1, 64);
    lsum += __shfl_xor(lsum, 2, 64);
    float o[32];
    #pragma unroll
    for (int d = 0; d < 32; ++d) o[d] = 0.f;
    #pragma unroll
    for (int j0 = 0; j0 < 16; ++j0){
      const int j = kq*16 + j0;
      const float pm = s[j0];
      #pragma unroll
      for (int dd = 0; dd < 8; ++dd){
        const float4 vv = *(const float4*)&vs[j*36 + dd*4];
        o[dd*4+0] += pm*vv.x; o[dd*4+1] += pm*vv.y;
        o[dd*4+2] += pm*vv.z; o[dd*4+3] += pm*vv.w;
      }
    }
    #pragma unroll
    for (int d = 0; d < 32; ++d){
      o[d] += __shfl_xor(o[d], 1, 64);
      o[d] += __shfl_xor(o[d], 2, 64);
    }
    const float inv = 1.f / lsum;
    const size_t obase = ((size_t)(b*256 + h*32 + kq*8))*4096 + pix;
    #pragma unroll
    for (int dd = 0; dd < 8; ++dd){
      xout[obase + (size_t)dd*4096] = o[kq*8 + dd]*inv;
      vout[obase + (size_t)dd*4096] = f2bf(vs[tn*36 + kq*8 + dd]);
    }
    __syncthreads();
  }
}

// ---------------------------------------------------------------------------
// Kernel 4: depthwise 7x7 conv on vimg(bf16) + residual, IN PLACE on io fp32.
// ---------------------------------------------------------------------------
__global__ void k_dwconv(const u16* __restrict__ vimg, const float* __restrict__ dww,
                         float* __restrict__ io){
  const int b = blockIdx.x >> 8, c = blockIdx.x & 255;
  __shared__ float tile[70*72];   // zero-padded halo
  __shared__ float wt[49];
  const size_t base = ((size_t)(b*256 + c)) * 4096;
  for (int i = threadIdx.x; i < 70*72; i += 256) tile[i] = 0.f;
  if (threadIdx.x < 49) wt[threadIdx.x] = dww[c*49 + threadIdx.x];
  __syncthreads();
  for (int i = threadIdx.x; i < 4096; i += 256){
    const int y = i >> 6, xx = i & 63;
    tile[(y+3)*72 + (xx+3)] = bf2f(vimg[base + i]);
  }
  __syncthreads();
  for (int i = threadIdx.x; i < 4096; i += 256){
    const int y = i >> 6, xx = i & 63;
    float acc = 0.f;
    #pragma unroll
    for (int ky = 0; ky < 7; ++ky)
      #pragma unroll
      for (int kx = 0; kx < 7; ++kx)
        acc += wt[ky*7 + kx] * tile[(y+ky)*72 + (xx+kx)];
    io[base + i] = acc + io[base + i];
  }
}

// ---------------------------------------------------------------------------
// Kernel 5: proj GEMM per image row (MFMA), IN PLACE on io fp32.
// Block (b,y) stages its full input slice io[b][:][y][:] into LDS (bf16)
// before writing the same slice — race-free within block.
// ---------------------------------------------------------------------------
__global__ void k_proj(const u16* __restrict__ pwb, const float* __restrict__ pb,
                       float* __restrict__ io){
  const int row = blockIdx.x;           // b*64 + y
  const int b = row >> 6, y = row & 63;
  __shared__ __align__(16) u16 ts[64*264];   // [pixel n][c] bf16, pad +8
  const float* tbase = io + (size_t)b*256*4096 + (size_t)y*64;
  for (int i = threadIdx.x; i < 16384; i += 256){
    const int c = i >> 6, n = i & 63;
    ts[n*264 + c] = f2bf(tbase[(size_t)c*4096 + n]);
  }
  __syncthreads();
  const int wave = threadIdx.x >> 6, lane = threadIdx.x & 63;
  const int quad = lane >> 4, l16 = lane & 15;
  for (int oi = 0; oi < 4; ++oi){
    const int ot = wave*4 + oi;          // 16 o-tiles of 16
    const int orow = ot*16 + l16;
    bf16x8 af[8];
    #pragma unroll
    for (int kc = 0; kc < 8; ++kc)
      af[kc] = *reinterpret_cast<const bf16x8*>(pwb + (size_t)orow*256 + kc*32 + quad*8);
    #pragma unroll
    for (int nt = 0; nt < 4; ++nt){
      f32x4 acc = {0.f, 0.f, 0.f, 0.f};
      #pragma unroll
      for (int kc = 0; kc < 8; ++kc){
        bf16x8 bf = *reinterpret_cast<const bf16x8*>(&ts[(nt*16 + l16)*264 + kc*32 + quad*8]);
        acc = __builtin_amdgcn_mfma_f32_16x16x32_bf16(af[kc], bf, acc, 0, 0, 0);
      }
      #pragma unroll
      for (int r = 0; r < 4; ++r){
        const int o = ot*16 + quad*4 + r;
        io[((size_t)(b*256 + o))*4096 + (size_t)y*64 + nt*16 + l16] = acc[r] + pb[o];
      }
    }
  }
}

// ---------------------------------------------------------------------------
extern "C" void kernel_launch(void* const* d_in, const int* in_sizes, int n_in,
                              void* d_out, int out_size, void* d_ws, size_t ws_size,
                              hipStream_t stream){
  const float* x   = (const float*)d_in[0];
  const float* qw  = (const float*)d_in[1];
  const float* qb  = (const float*)d_in[2];
  const float* pw  = (const float*)d_in[3];
  const float* pb  = (const float*)d_in[4];
  const float* w1  = (const float*)d_in[5];
  const float* b1  = (const float*)d_in[6];
  const float* w2  = (const float*)d_in[7];
  const float* dww = (const float*)d_in[8];

  // ws layout (~34.2 MB): tab 8KB | biasT 128KB | qwb 384KB | pwb 128KB | vimg 32MB
  char* ws = (char*)d_ws;
  float* tab   = (float*)(ws);
  float* biasT = (float*)(ws + 8192);
  u16*   qwb   = (u16*)  (ws + 139264);
  u16*   pwb   = (u16*)  (ws + 532480);
  u16*   vimg  = (u16*)  (ws + 663552);
  float* out   = (float*)d_out;          // doubles as attn-out intermediate

  k_cvt_w      <<<1024, 256, 0, stream>>>(qw, pw, qwb, pwb);
  k_cpb_mlp    <<<225,  256, 0, stream>>>(w1, b1, w2, tab);
  k_bias_expand<<<128,  256, 0, stream>>>(tab, biasT);
  k_qkv_attn   <<<1024, 256, 0, stream>>>(x, qwb, qb, biasT, out, vimg);
  k_dwconv     <<<4096, 256, 0, stream>>>(vimg, dww, out);
  k_proj       <<<1024, 256, 0, stream>>>(pwb, pb, out);
}

// Round 8
// 451.285 us; speedup vs baseline: 1.8117x; 1.8117x over previous
//
#include <hip/hip_runtime.h>
#include <cstdint>
#include <cstddef>

typedef unsigned short u16;
typedef unsigned int   u32;

#define LW     15
#define BNS    0.9999950000374997f   /* 1/sqrt(1+1e-5) */
#define SCALE  0.17677669529663687f  /* 1/sqrt(32) */

typedef __bf16 bf16x8 __attribute__((ext_vector_type(8)));
typedef float  f32x4  __attribute__((ext_vector_type(4)));

__device__ __forceinline__ u16 f2bf(float f){
  union { float f; u32 i; } v; v.f = f;
  u32 r = v.i + 0x7FFFu + ((v.i >> 16) & 1u);
  return (u16)(r >> 16);
}
__device__ __forceinline__ float bf2f(u16 u){
  union { u32 i; float f; } v; v.i = ((u32)u) << 16; return v.f;
}

// ---------------------------------------------------------------------------
// Kernel 0: convert qkv_w (196608) and proj_w (65536) fp32 -> bf16 in ws
// ---------------------------------------------------------------------------
__global__ void k_cvt_w(const float* __restrict__ qw, const float* __restrict__ pw,
                        u16* __restrict__ qwb, u16* __restrict__ pwb){
  const int i = blockIdx.x*256 + threadIdx.x;
  if (i < 196608) qwb[i] = f2bf(qw[i]);
  else            pwb[i - 196608] = f2bf(pw[i - 196608]);
}

// ---------------------------------------------------------------------------
// Kernel 1: CPB MLP -> tab[225][8] fp32
// ---------------------------------------------------------------------------
__global__ void k_cpb_mlp(const float* __restrict__ w1, const float* __restrict__ b1,
                          const float* __restrict__ w2, float* __restrict__ tab){
  const int e = blockIdx.x;        // 0..224
  const int c = threadIdx.x;       // 0..255
  const float a0 = (float)(e / LW - 7);
  const float a1 = (float)(e % LW - 7);
  const float cx = copysignf(log2f(fabsf(a0)*(8.f/7.f) + 1.f) * (1.f/3.f), a0);
  const float cy = copysignf(log2f(fabsf(a1)*(8.f/7.f) + 1.f) * (1.f/3.f), a1);
  float pre = (cx*w1[2*c] + cy*w1[2*c+1] + b1[c]) * BNS;
  float hid = pre / (1.f + __expf(-pre));   // silu
  __shared__ float hl[256];
  hl[c] = hid;
  __syncthreads();
  if (c < 8){
    float s = 0.f;
    for (int i = 0; i < 256; ++i) s += hl[i] * w2[c*256 + i];
    tab[e*8 + c] = s * BNS;
  }
}

// ---------------------------------------------------------------------------
// Kernel 2: biasT[h][key m][query n] = 16*sigmoid(tab[rpi(n,m)][h])
// ---------------------------------------------------------------------------
__global__ void k_bias_expand(const float* __restrict__ tab, float* __restrict__ biasT){
  const int id = blockIdx.x*256 + threadIdx.x;   // h*4096 + m*64 + n
  const int nq = id & 63;          // query token
  const int m  = (id >> 6) & 63;   // key token
  const int h  = id >> 12;
  const int dy = (nq >> 3) - (m >> 3) + 7;
  const int dx = (nq & 7)  - (m & 7)  + 7;
  const float v = tab[(dy*LW + dx)*8 + h];
  biasT[id] = 16.f / (1.f + __expf(-v));
}

// ---------------------------------------------------------------------------
// Kernel 3: fused qkv GEMM + MFMA windowed attention.
// Block = window, 256 thr = 4 waves; wave w owns token/query tile w (16).
// xs is DEAD after bfr register loads -> attention buffers overlay it.
// LDS total 33792 B => 4 blocks/CU. All b128 rows are 16B-multiples.
//   phase 1: xs   u16[64][264] @0
//   phase 2: q_b  u16[64][40] @0     | ks_ u16[64][40] @5120
//            vsT  u16[32][72] @10240 | Pb  u16[64][72] @14848 (key dim = 64!)
//            linv f32[64]     @24064 | obuf f32[32][72] @24320 (ends 33536)
// ---------------------------------------------------------------------------
__global__ __launch_bounds__(256) void k_qkv_attn(
    const float* __restrict__ x, const u16* __restrict__ qwb,
    const float* __restrict__ qb, const float* __restrict__ biasT,
    float* __restrict__ xout, u16* __restrict__ vout){
  const int win = blockIdx.x;
  const int b = win >> 6, wy = (win >> 3) & 7, wx = win & 7;
  __shared__ __align__(16) char smem[33792];
  u16*   xs   = (u16*)(smem);
  u16*   q_b  = (u16*)(smem);
  u16*   ks_  = (u16*)(smem + 5120);
  u16*   vsT  = (u16*)(smem + 10240);
  u16*   Pb   = (u16*)(smem + 14848);
  float* linv = (float*)(smem + 24064);
  float* obuf = (float*)(smem + 24320);

  const float* xbase = x + (size_t)b*256*4096 + (size_t)(wy*8)*64 + wx*8;
  for (int i = threadIdx.x; i < 16384; i += 256){
    const int c = i >> 6, n = i & 63;
    xs[n*264 + c] = f2bf(xbase[(size_t)c*4096 + ((n>>3)<<6) + (n&7)]);
  }
  const int wave = threadIdx.x >> 6, lane = threadIdx.x & 63;
  const int quad = lane >> 4, l16 = lane & 15;
  __syncthreads();

  // B-fragments of x for this wave's token tile; xs is dead afterwards.
  bf16x8 bfr[8];
  #pragma unroll
  for (int kc = 0; kc < 8; ++kc)
    bfr[kc] = *(const bf16x8*)&xs[(wave*16 + l16)*264 + kc*32 + quad*8];
  __syncthreads();   // all bfr loads done before q_b/ks_ overwrite xs

  // epilogue indexing
  const int ed = threadIdx.x >> 3;           // 0..31 (d)
  const int eq = (threadIdx.x & 7) * 8;      // query group start
  const size_t epix = (size_t)(wy*8 + (threadIdx.x & 7))*64 + wx*8;

  const f32x4 zero4 = {0.f, 0.f, 0.f, 0.f};

  for (int h = 0; h < 8; ++h){
    // ---- qkv GEMM: 96 rows (q0..31,k,v) x this wave's 16 tokens, K=256 ----
    #pragma unroll
    for (int ot = 0; ot < 6; ++ot){
      const int rowa = ot*16 + l16;                         // A row (0..95)
      const int oga = (rowa >> 5)*256 + h*32 + (rowa & 31); // weight row
      f32x4 acc = zero4;
      #pragma unroll
      for (int kc = 0; kc < 8; ++kc){
        bf16x8 af = *(const bf16x8*)(qwb + (size_t)oga*256 + kc*32 + quad*8);
        acc = __builtin_amdgcn_mfma_f32_16x16x32_bf16(af, bfr[kc], acc, 0, 0, 0);
      }
      const int tok = wave*16 + l16;       // D col
      const int db  = ot*16 + quad*4;      // D rows db..db+3 (within 96)
      if (ot < 2){                 // q dims
        ushort4 pk;
        pk.x = f2bf(acc[0] + qb[h*32 + (db&31) + 0]);
        pk.y = f2bf(acc[1] + qb[h*32 + (db&31) + 1]);
        pk.z = f2bf(acc[2] + qb[h*32 + (db&31) + 2]);
        pk.w = f2bf(acc[3] + qb[h*32 + (db&31) + 3]);
        *(ushort4*)&q_b[tok*40 + (db & 31)] = pk;
      } else if (ot < 4){          // k dims
        ushort4 pk;
        pk.x = f2bf(acc[0] + qb[256 + h*32 + (db&31) + 0]);
        pk.y = f2bf(acc[1] + qb[256 + h*32 + (db&31) + 1]);
        pk.z = f2bf(acc[2] + qb[256 + h*32 + (db&31) + 2]);
        pk.w = f2bf(acc[3] + qb[256 + h*32 + (db&31) + 3]);
        *(ushort4*)&ks_[tok*40 + (db & 31)] = pk;
      } else {                     // v dims -> transposed vsT[d][tok]
        #pragma unroll
        for (int r = 0; r < 4; ++r){
          const int d = (db & 31) + r;
          vsT[d*72 + tok] = f2bf(acc[r] + qb[512 + h*32 + d]);
        }
      }
    }
    __syncthreads();

    // ---- QK^T: S[key][query] for this wave's 16 queries ----
    bf16x8 qf = *(const bf16x8*)&q_b[(wave*16 + l16)*40 + quad*8];
    f32x4 st[4];
    #pragma unroll
    for (int kt = 0; kt < 4; ++kt){
      bf16x8 ka = *(const bf16x8*)&ks_[(kt*16 + l16)*40 + quad*8];
      st[kt] = __builtin_amdgcn_mfma_f32_16x16x32_bf16(ka, qf, zero4, 0, 0, 0);
    }
    const int qn = wave*16 + l16;
    float sc[16], mx = -1e30f;
    #pragma unroll
    for (int kt = 0; kt < 4; ++kt)
      #pragma unroll
      for (int r = 0; r < 4; ++r){
        const int key = kt*16 + quad*4 + r;
        const float v = st[kt][r]*SCALE + biasT[(h<<12) + (key<<6) + qn];
        sc[kt*4+r] = v; mx = fmaxf(mx, v);
      }
    mx = fmaxf(mx, __shfl_xor(mx, 16));
    mx = fmaxf(mx, __shfl_xor(mx, 32));
    float sum = 0.f;
    #pragma unroll
    for (int i = 0; i < 16; ++i){ sc[i] = __expf(sc[i] - mx); sum += sc[i]; }
    sum += __shfl_xor(sum, 16);
    sum += __shfl_xor(sum, 32);
    if (quad == 0) linv[wave*16 + l16] = 1.f / sum;
    // P[query][key] bf16 (unnormalized); row stride 72 covers key=0..63
    #pragma unroll
    for (int kt = 0; kt < 4; ++kt){
      ushort4 pk;
      pk.x = f2bf(sc[kt*4+0]); pk.y = f2bf(sc[kt*4+1]);
      pk.z = f2bf(sc[kt*4+2]); pk.w = f2bf(sc[kt*4+3]);
      *(ushort4*)&Pb[qn*72 + kt*16 + quad*4] = pk;
    }
    __syncthreads();

    // ---- PV: O[query][d] ----
    bf16x8 pa0 = *(const bf16x8*)&Pb[(wave*16 + l16)*72 +  0 + quad*8];
    bf16x8 pa1 = *(const bf16x8*)&Pb[(wave*16 + l16)*72 + 32 + quad*8];
    #pragma unroll
    for (int dt = 0; dt < 2; ++dt){
      bf16x8 bv0 = *(const bf16x8*)&vsT[(dt*16 + l16)*72 +  0 + quad*8];
      bf16x8 bv1 = *(const bf16x8*)&vsT[(dt*16 + l16)*72 + 32 + quad*8];
      f32x4 o = __builtin_amdgcn_mfma_f32_16x16x32_bf16(pa0, bv0, zero4, 0, 0, 0);
      o = __builtin_amdgcn_mfma_f32_16x16x32_bf16(pa1, bv1, o, 0, 0, 0);
      #pragma unroll
      for (int r = 0; r < 4; ++r){
        const float ls = linv[wave*16 + quad*4 + r];
        obuf[(dt*16 + l16)*72 + wave*16 + quad*4 + r] = o[r]*ls;
      }
    }
    __syncthreads();

    // ---- epilogue: coalesced O (fp32) + V (bf16) stores ----
    {
      const size_t gp = ((size_t)(b*256 + h*32 + ed))*4096 + epix;
      float4 o0 = *(const float4*)&obuf[ed*72 + eq];
      float4 o1 = *(const float4*)&obuf[ed*72 + eq + 4];
      *(float4*)&xout[gp]     = o0;
      *(float4*)&xout[gp + 4] = o1;
      ushort4 v0 = *(const ushort4*)&vsT[ed*72 + eq];
      ushort4 v1 = *(const ushort4*)&vsT[ed*72 + eq + 4];
      *(ushort4*)&vout[gp]     = v0;
      *(ushort4*)&vout[gp + 4] = v1;
    }
    __syncthreads();   // protect LDS before next head's GEMM overwrites
  }
}

// ---------------------------------------------------------------------------
// Kernel 4: depthwise 7x7 + residual, IN PLACE on io (fp32).
// Register-blocked: thread computes 4x4 outputs; 30 b128 LDS reads vs 784.
// ---------------------------------------------------------------------------
__global__ __launch_bounds__(256) void k_dwconv(
    const u16* __restrict__ vimg, const float* __restrict__ dww,
    float* __restrict__ io){
  const int b = blockIdx.x >> 8, c = blockIdx.x & 255;
  __shared__ float tile[70*72];   // zero-padded halo
  const size_t base = ((size_t)(b*256 + c)) * 4096;
  for (int i = threadIdx.x; i < 70*72; i += 256) tile[i] = 0.f;
  float w[49];
  #pragma unroll
  for (int j = 0; j < 49; ++j) w[j] = dww[c*49 + j];
  __syncthreads();
  for (int i = threadIdx.x; i < 4096; i += 256){
    const int y = i >> 6, xx = i & 63;
    tile[(y+3)*72 + (xx+3)] = bf2f(vimg[base + i]);
  }
  __syncthreads();

  const int x0 = (threadIdx.x & 15) * 4;
  const int y0 = (threadIdx.x >> 4) * 4;
  float acc[4][4];
  #pragma unroll
  for (int i = 0; i < 4; ++i)
    #pragma unroll
    for (int j = 0; j < 4; ++j) acc[i][j] = 0.f;

  #pragma unroll
  for (int ty = 0; ty < 10; ++ty){
    const float* rp = &tile[(y0 + ty)*72 + x0];
    float r[12];
    *(float4*)&r[0] = *(const float4*)&rp[0];
    *(float4*)&r[4] = *(const float4*)&rp[4];
    *(float4*)&r[8] = *(const float4*)&rp[8];
    #pragma unroll
    for (int oy = 0; oy < 4; ++oy){
      if (ty >= oy && ty - oy <= 6){
        const int ky = ty - oy;
        #pragma unroll
        for (int ox = 0; ox < 4; ++ox)
          #pragma unroll
          for (int kx = 0; kx < 7; ++kx)
            acc[oy][ox] += w[ky*7 + kx] * r[ox + kx];
      }
    }
  }
  #pragma unroll
  for (int oy = 0; oy < 4; ++oy){
    const size_t gi = base + (size_t)(y0 + oy)*64 + x0;
    float4 res = *(const float4*)&io[gi];
    res.x += acc[oy][0]; res.y += acc[oy][1];
    res.z += acc[oy][2]; res.w += acc[oy][3];
    *(float4*)&io[gi] = res;
  }
}

// ---------------------------------------------------------------------------
// Kernel 5: proj GEMM per image row (MFMA), IN PLACE on io fp32.
// ---------------------------------------------------------------------------
__global__ void k_proj(const u16* __restrict__ pwb, const float* __restrict__ pb,
                       float* __restrict__ io){
  const int row = blockIdx.x;           // b*64 + y
  const int b = row >> 6, y = row & 63;
  __shared__ __align__(16) u16 ts[64*264];   // [pixel n][c] bf16, pad +8
  const float* tbase = io + (size_t)b*256*4096 + (size_t)y*64;
  for (int i = threadIdx.x; i < 16384; i += 256){
    const int c = i >> 6, n = i & 63;
    ts[n*264 + c] = f2bf(tbase[(size_t)c*4096 + n]);
  }
  __syncthreads();
  const int wave = threadIdx.x >> 6, lane = threadIdx.x & 63;
  const int quad = lane >> 4, l16 = lane & 15;
  for (int oi = 0; oi < 4; ++oi){
    const int ot = wave*4 + oi;          // 16 o-tiles of 16
    const int orow = ot*16 + l16;
    bf16x8 af[8];
    #pragma unroll
    for (int kc = 0; kc < 8; ++kc)
      af[kc] = *reinterpret_cast<const bf16x8*>(pwb + (size_t)orow*256 + kc*32 + quad*8);
    #pragma unroll
    for (int nt = 0; nt < 4; ++nt){
      f32x4 acc = {0.f, 0.f, 0.f, 0.f};
      #pragma unroll
      for (int kc = 0; kc < 8; ++kc){
        bf16x8 bf = *reinterpret_cast<const bf16x8*>(&ts[(nt*16 + l16)*264 + kc*32 + quad*8]);
        acc = __builtin_amdgcn_mfma_f32_16x16x32_bf16(af[kc], bf, acc, 0, 0, 0);
      }
      #pragma unroll
      for (int r = 0; r < 4; ++r){
        const int o = ot*16 + quad*4 + r;
        io[((size_t)(b*256 + o))*4096 + (size_t)y*64 + nt*16 + l16] = acc[r] + pb[o];
      }
    }
  }
}

// ---------------------------------------------------------------------------
extern "C" void kernel_launch(void* const* d_in, const int* in_sizes, int n_in,
                              void* d_out, int out_size, void* d_ws, size_t ws_size,
                              hipStream_t stream){
  const float* x   = (const float*)d_in[0];
  const float* qw  = (const float*)d_in[1];
  const float* qb  = (const float*)d_in[2];
  const float* pw  = (const float*)d_in[3];
  const float* pb  = (const float*)d_in[4];
  const float* w1  = (const float*)d_in[5];
  const float* b1  = (const float*)d_in[6];
  const float* w2  = (const float*)d_in[7];
  const float* dww = (const float*)d_in[8];

  // ws: tab 8KB | biasT 128KB | qwb 384KB | pwb 128KB | vimg 32MB (~34.2 MB)
  char* ws = (char*)d_ws;
  float* tab   = (float*)(ws);
  float* biasT = (float*)(ws + 8192);
  u16*   qwb   = (u16*)  (ws + 139264);
  u16*   pwb   = (u16*)  (ws + 532480);
  u16*   vimg  = (u16*)  (ws + 663552);
  float* out   = (float*)d_out;          // doubles as attn-out intermediate

  k_cvt_w      <<<1024, 256, 0, stream>>>(qw, pw, qwb, pwb);
  k_cpb_mlp    <<<225,  256, 0, stream>>>(w1, b1, w2, tab);
  k_bias_expand<<<128,  256, 0, stream>>>(tab, biasT);
  k_qkv_attn   <<<1024, 256, 0, stream>>>(x, qwb, qb, biasT, out, vimg);
  k_dwconv     <<<4096, 256, 0, stream>>>(vimg, dww, out);
  k_proj       <<<1024, 256, 0, stream>>>(pwb, pb, out);
}